// Round 5
// baseline (179.122 us; speedup 1.0000x reference)
//
#include <hip/hip_runtime.h>
#include <hip/hip_bf16.h>

#define NROW 8192
#define DIM  128
#define JSPLIT 16
#define NBLK (64 * JSPLIT)   // 1024 blocks
#define BIGF 1e30f

typedef __attribute__((ext_vector_type(8))) short bf16x8;
typedef __attribute__((ext_vector_type(4))) float f32x4;

// ws layout:
//   [0, 2 MB)      xbT  : fragment-major bf16 (A operand)
//   [2, 4 MB)      xbM2 : same layout, values scaled by -2 (B operand)
//   [4 MB, +64 KB) meta : uint2 { float bits sq[j], lbl[j] }
//   +32 KB posb, +32 KB negb, +16 B counter
// fragment chunk: tile*2048 + ks*512 + lane*8 (ushorts); lane=quad*16+l15
// holds rows tile*16+l15, cols ks*32+quad*8..+7

__device__ __forceinline__ unsigned short f2bf(float f) {
    unsigned u = __float_as_uint(f);
    return (unsigned short)((u + 0x7fffu + ((u >> 16) & 1u)) >> 16);   // RNE
}

__global__ __launch_bounds__(256) void prep_kernel(const float* __restrict__ x,
                                                   const int* __restrict__ lbl,
                                                   unsigned short* __restrict__ xbT,
                                                   unsigned short* __restrict__ xbM2,
                                                   uint2* __restrict__ meta,
                                                   unsigned* __restrict__ posb,
                                                   unsigned* __restrict__ negb,
                                                   unsigned* __restrict__ counter,
                                                   float* __restrict__ out) {
    __shared__ unsigned short Al[32][136];
    __shared__ unsigned short Ml[32][136];
    __shared__ float sqp[32][8];

    const int b = blockIdx.x, t = threadIdx.x;
    const int gid = b * 256 + t;
    if (gid < NROW) { posb[gid] = 0u; negb[gid] = __float_as_uint(BIGF); }
    if (gid == 0)   { counter[0] = 0u; out[0] = 0.0f; }

    const int R0  = b * 32;
    const int r   = t >> 3;
    const int seg = t & 7;
    const float* src = x + (size_t)(R0 + r) * DIM + seg * 16;

    float s = 0.0f;
    #pragma unroll
    for (int c4 = 0; c4 < 4; c4++) {
        float4 v = *(const float4*)(src + c4 * 4);
        s += v.x * v.x + v.y * v.y + v.z * v.z + v.w * v.w;
        uint2 ua, um;
        ua.x = (unsigned)f2bf(v.x) | ((unsigned)f2bf(v.y) << 16);
        ua.y = (unsigned)f2bf(v.z) | ((unsigned)f2bf(v.w) << 16);
        um.x = (unsigned)f2bf(-2.0f * v.x) | ((unsigned)f2bf(-2.0f * v.y) << 16);
        um.y = (unsigned)f2bf(-2.0f * v.z) | ((unsigned)f2bf(-2.0f * v.w) << 16);
        *(uint2*)&Al[r][seg * 16 + c4 * 4] = ua;
        *(uint2*)&Ml[r][seg * 16 + c4 * 4] = um;
    }
    sqp[r][seg] = s;
    __syncthreads();

    if (t < 32) {
        float ss = 0.0f;
        #pragma unroll
        for (int q = 0; q < 8; q++) ss += sqp[t][q];
        uint2 mv;
        mv.x = __float_as_uint(ss);
        mv.y = (unsigned)lbl[R0 + t];
        meta[R0 + t] = mv;
    }

    const int ks = t >> 6, lane = t & 63;
    const int q = lane >> 4, l = lane & 15;
    #pragma unroll
    for (int tl = 0; tl < 2; tl++) {
        int row = tl * 16 + l, col = ks * 32 + q * 8;
        uint4 va = *(const uint4*)&Al[row][col];
        uint4 vm = *(const uint4*)&Ml[row][col];
        size_t off = (size_t)(R0 / 16 + tl) * 2048 + ks * 512 + lane * 8;
        *(uint4*)(xbT  + off) = va;
        *(uint4*)(xbM2 + off) = vm;
    }
}

__global__ __launch_bounds__(256, 2) void tri_mfma(const unsigned short* __restrict__ xbT,
                                                   const unsigned short* __restrict__ xbM2,
                                                   const uint2* __restrict__ meta,
                                                   unsigned* __restrict__ posb,
                                                   unsigned* __restrict__ negb,
                                                   unsigned* __restrict__ counter,
                                                   const float* __restrict__ margin,
                                                   float* __restrict__ out) {
    const int bid  = blockIdx.x;
    const int rb   = bid >> 4;           // 0..63
    const int jq   = bid & 15;           // 0..15
    const int i0   = rb * 128;
    const int t    = threadIdx.x;
    const int lane = t & 63;
    const int w    = t >> 6;
    const int wrow = (w >> 1) * 64;
    const int wcol = (w & 1) * 64;
    const int quad = lane >> 4;
    const int l15  = lane & 15;
    const int rtb  = (i0 + wrow) >> 4;   // row tile base index
    const int dr   = l15 - quad * 4;     // diag element when dr == r (ti == tdiff)

    // A fragments resident in 64 VGPRs
    bf16x8 A[4][4];
    #pragma unroll
    for (int ti = 0; ti < 4; ti++)
        #pragma unroll
        for (int ks = 0; ks < 4; ks++)
            A[ti][ks] = *(const bf16x8*)(xbT + ((size_t)(rtb + ti) * 2048 + ks * 512 + lane * 8));

    // row labels only (sq_i reloaded after the loop)
    int lbli[4][4];
    #pragma unroll
    for (int ti = 0; ti < 4; ti++) {
        int rbase = i0 + wrow + ti * 16 + quad * 4;
        uint4 m01 = *(const uint4*)(meta + rbase);
        uint4 m23 = *(const uint4*)(meta + rbase + 2);
        lbli[ti][0] = (int)m01.y; lbli[ti][1] = (int)m01.w;
        lbli[ti][2] = (int)m23.y; lbli[ti][3] = (int)m23.w;
    }

    float posm[4][4], negm[4][4];
    #pragma unroll
    for (int ti = 0; ti < 4; ti++)
        #pragma unroll
        for (int r = 0; r < 4; r++) { posm[ti][r] = -BIGF; negm[ti][r] = BIGF; }

    // wave's 16 column tiles: tau -> ctile = cb + (tau>>2)*8 + (tau&3)
    const int cb = (jq * (NROW / JSPLIT) + wcol) >> 4;

    auto ctof = [&](int tau) { return cb + ((tau >> 2) << 3) + (tau & 3); };

    auto compute = [&](int ct, const bf16x8* B, uint2 mv) {
        float sqj = __uint_as_float(mv.x);
        int lblj  = (int)mv.y;
        f32x4 acc[4];
        #pragma unroll
        for (int ti = 0; ti < 4; ti++) acc[ti] = (f32x4){sqj, sqj, sqj, sqj};
        #pragma unroll
        for (int ks = 0; ks < 4; ks++)
            #pragma unroll
            for (int ti = 0; ti < 4; ti++)
                acc[ti] = __builtin_amdgcn_mfma_f32_16x16x32_bf16(A[ti][ks], B[ks], acc[ti], 0, 0, 0);
        // acc = sq_j - 2*dot
        int td = ct - rtb;
        if ((unsigned)td >= 4u) {
            #pragma unroll
            for (int ti = 0; ti < 4; ti++)
                #pragma unroll
                for (int r = 0; r < 4; r++) {
                    float s = acc[ti][r];
                    bool same = (lbli[ti][r] == lblj);
                    posm[ti][r] = fmaxf(posm[ti][r], same ? s : -BIGF);
                    negm[ti][r] = fminf(negm[ti][r], same ? BIGF : s);
                }
        } else {
            #pragma unroll
            for (int ti = 0; ti < 4; ti++)
                #pragma unroll
                for (int r = 0; r < 4; r++) {
                    float s = acc[ti][r];
                    bool same = (lbli[ti][r] == lblj);
                    bool isd  = (ti == td) && (dr == r);
                    posm[ti][r] = fmaxf(posm[ti][r], (same && !isd) ? s : -BIGF);
                    negm[ti][r] = fminf(negm[ti][r], same ? BIGF : s);
                }
        }
    };

    // register double-buffered pipeline over 16 column tiles
    bf16x8 Bc[4], Bn[4];
    uint2 mc, mn;
    int c = ctof(0);
    #pragma unroll
    for (int ks = 0; ks < 4; ks++)
        Bc[ks] = *(const bf16x8*)(xbM2 + ((size_t)c * 2048 + ks * 512 + lane * 8));
    mc = meta[c * 16 + l15];

    #pragma unroll 1
    for (int tau = 0; tau < 16; tau += 2) {
        int c1 = ctof(tau + 1);
        #pragma unroll
        for (int ks = 0; ks < 4; ks++)
            Bn[ks] = *(const bf16x8*)(xbM2 + ((size_t)c1 * 2048 + ks * 512 + lane * 8));
        mn = meta[c1 * 16 + l15];
        compute(c, Bc, mc);

        int c2 = ctof((tau + 2) & 15);
        #pragma unroll
        for (int ks = 0; ks < 4; ks++)
            Bc[ks] = *(const bf16x8*)(xbM2 + ((size_t)c2 * 2048 + ks * 512 + lane * 8));
        mc = meta[c2 * 16 + l15];
        compute(c1, Bn, mn);
        c = c2;
    }

    // reload sq_i, reduce across 16 column-lanes, one atomic pair per row
    #pragma unroll
    for (int ti = 0; ti < 4; ti++) {
        int rbase = i0 + wrow + ti * 16 + quad * 4;
        uint4 m01 = *(const uint4*)(meta + rbase);
        uint4 m23 = *(const uint4*)(meta + rbase + 2);
        float sqi[4] = {__uint_as_float(m01.x), __uint_as_float(m01.z),
                        __uint_as_float(m23.x), __uint_as_float(m23.z)};
        #pragma unroll
        for (int r = 0; r < 4; r++) {
            float p = posm[ti][r];
            float n = negm[ti][r];
            #pragma unroll
            for (int m = 8; m >= 1; m >>= 1) {
                p = fmaxf(p, __shfl_xor(p, m));
                n = fminf(n, __shfl_xor(n, m));
            }
            if (l15 == 0) {
                int row = i0 + wrow + ti * 16 + quad * 4 + r;
                float d2p = fmaxf(0.0f, sqi[r] + p);   // no positive -> 0
                float d2n = fmaxf(0.0f, sqi[r] + n);   // clamp bf16-noise negatives
                atomicMax(&posb[row], __float_as_uint(d2p));
                atomicMin(&negb[row], __float_as_uint(d2n));
            }
        }
    }

    // fused finalization: last block computes the loss
    __threadfence();
    __shared__ unsigned lastflag;
    __shared__ float wsum[4];
    __syncthreads();
    if (t == 0) {
        unsigned prev = __hip_atomic_fetch_add(counter, 1u, __ATOMIC_ACQ_REL, __HIP_MEMORY_SCOPE_AGENT);
        lastflag = (prev == NBLK - 1) ? 1u : 0u;
    }
    __syncthreads();
    if (lastflag) {
        __threadfence();
        float mg = margin[0];
        float loss = 0.0f;
        for (int row = t; row < NROW; row += 256) {
            unsigned pb = __hip_atomic_load(&posb[row], __ATOMIC_RELAXED, __HIP_MEMORY_SCOPE_AGENT);
            unsigned nb = __hip_atomic_load(&negb[row], __ATOMIC_RELAXED, __HIP_MEMORY_SCOPE_AGENT);
            float p  = sqrtf(__uint_as_float(pb));
            float ng = sqrtf(__uint_as_float(nb));
            loss += fmaxf(p - ng + mg, 0.0f);
        }
        #pragma unroll
        for (int o = 32; o > 0; o >>= 1) loss += __shfl_down(loss, o);
        if (lane == 0) wsum[w] = loss;
        __syncthreads();
        if (t == 0) out[0] = (wsum[0] + wsum[1] + wsum[2] + wsum[3]) * (1.0f / (float)NROW);
    }
}

extern "C" void kernel_launch(void* const* d_in, const int* in_sizes, int n_in,
                              void* d_out, int out_size, void* d_ws, size_t ws_size,
                              hipStream_t stream) {
    const float* x      = (const float*)d_in[0];
    const int*   lbl    = (const int*)d_in[1];
    const float* margin = (const float*)d_in[2];
    float* out = (float*)d_out;

    const size_t MAT = (size_t)NROW * DIM * 2;
    unsigned short* xbT  = (unsigned short*)d_ws;
    unsigned short* xbM2 = (unsigned short*)((char*)d_ws + MAT);
    uint2*    meta = (uint2*)((char*)d_ws + 2 * MAT);
    unsigned* posb = (unsigned*)((char*)meta + NROW * 8);
    unsigned* negb = posb + NROW;
    unsigned* counter = negb + NROW;

    prep_kernel<<<NROW / 32, 256, 0, stream>>>(x, lbl, xbT, xbM2, meta, posb, negb, counter, out);
    tri_mfma<<<NBLK, 256, 0, stream>>>(xbT, xbM2, meta, posb, negb, counter, margin, out);
}

// Round 6
// 138.286 us; speedup vs baseline: 1.2953x; 1.2953x over previous
//
#include <hip/hip_runtime.h>
#include <hip/hip_bf16.h>

#define NROW 8192
#define DIM  128
#define JSPLIT 8
#define NBLK (64 * JSPLIT)   // 512 blocks
#define BIGF 1e30f

typedef __attribute__((ext_vector_type(8))) short bf16x8;
typedef __attribute__((ext_vector_type(4))) float f32x4;

// ws layout:
//   [0, 2 MB)      xbT  : fragment-major bf16 (A operand), tile*4096 B
//   [2, 4 MB)      xbM2 : same layout, values scaled by -2 (B operand)
//   [4 MB, +64 KB) meta : uint2 { float bits sq[j], lbl[j] }
//   +32 KB posb, +32 KB negb, +16 B counter
// fragment chunk: tile*2048 + ks*512 + lane*8 (ushorts); lane=quad*16+l15
// holds rows tile*16+l15, cols ks*32+quad*8..+7

__device__ __forceinline__ unsigned short f2bf(float f) {
    unsigned u = __float_as_uint(f);
    return (unsigned short)((u + 0x7fffu + ((u >> 16) & 1u)) >> 16);   // RNE
}

__device__ __forceinline__ void glds16(const void* g, void* l) {
    __builtin_amdgcn_global_load_lds(
        (const __attribute__((address_space(1))) void*)g,
        (__attribute__((address_space(3))) void*)l,
        16, 0, 0);
}

__global__ __launch_bounds__(256) void prep_kernel(const float* __restrict__ x,
                                                   const int* __restrict__ lbl,
                                                   unsigned short* __restrict__ xbT,
                                                   unsigned short* __restrict__ xbM2,
                                                   uint2* __restrict__ meta,
                                                   unsigned* __restrict__ posb,
                                                   unsigned* __restrict__ negb,
                                                   unsigned* __restrict__ counter,
                                                   float* __restrict__ out) {
    __shared__ unsigned short Al[32][136];
    __shared__ unsigned short Ml[32][136];
    __shared__ float sqp[32][8];

    const int b = blockIdx.x, t = threadIdx.x;
    const int gid = b * 256 + t;
    if (gid < NROW) { posb[gid] = 0u; negb[gid] = __float_as_uint(BIGF); }
    if (gid == 0)   { counter[0] = 0u; out[0] = 0.0f; }

    const int R0  = b * 32;
    const int r   = t >> 3;
    const int seg = t & 7;
    const float* src = x + (size_t)(R0 + r) * DIM + seg * 16;

    float s = 0.0f;
    #pragma unroll
    for (int c4 = 0; c4 < 4; c4++) {
        float4 v = *(const float4*)(src + c4 * 4);
        s += v.x * v.x + v.y * v.y + v.z * v.z + v.w * v.w;
        uint2 ua, um;
        ua.x = (unsigned)f2bf(v.x) | ((unsigned)f2bf(v.y) << 16);
        ua.y = (unsigned)f2bf(v.z) | ((unsigned)f2bf(v.w) << 16);
        um.x = (unsigned)f2bf(-2.0f * v.x) | ((unsigned)f2bf(-2.0f * v.y) << 16);
        um.y = (unsigned)f2bf(-2.0f * v.z) | ((unsigned)f2bf(-2.0f * v.w) << 16);
        *(uint2*)&Al[r][seg * 16 + c4 * 4] = ua;
        *(uint2*)&Ml[r][seg * 16 + c4 * 4] = um;
    }
    sqp[r][seg] = s;
    __syncthreads();

    if (t < 32) {
        float ss = 0.0f;
        #pragma unroll
        for (int q = 0; q < 8; q++) ss += sqp[t][q];
        uint2 mv;
        mv.x = __float_as_uint(ss);
        mv.y = (unsigned)lbl[R0 + t];
        meta[R0 + t] = mv;
    }

    const int ks = t >> 6, lane = t & 63;
    const int q = lane >> 4, l = lane & 15;
    #pragma unroll
    for (int tl = 0; tl < 2; tl++) {
        int row = tl * 16 + l, col = ks * 32 + q * 8;
        uint4 va = *(const uint4*)&Al[row][col];
        uint4 vm = *(const uint4*)&Ml[row][col];
        size_t off = (size_t)(R0 / 16 + tl) * 2048 + ks * 512 + lane * 8;
        *(uint4*)(xbT  + off) = va;
        *(uint4*)(xbM2 + off) = vm;
    }
}

__global__ __launch_bounds__(256, 2) void tri_mfma(const unsigned short* __restrict__ xbT,
                                                   const unsigned short* __restrict__ xbM2,
                                                   const uint2* __restrict__ meta,
                                                   unsigned* __restrict__ posb,
                                                   unsigned* __restrict__ negb,
                                                   unsigned* __restrict__ counter,
                                                   const float* __restrict__ margin,
                                                   float* __restrict__ out) {
    __shared__ uint4 Bbuf[2][2048];          // 2 x 32 KB, no padding (glds layout)

    const int bid  = blockIdx.x;
    const int rb   = bid >> 3;               // 0..63
    const int jq   = bid & 7;                // 0..7
    const int t    = threadIdx.x;
    const int lane = t & 63;
    const int w    = t >> 6;
    const int wrow2 = (w >> 1);              // 0/1: row-half of wave
    const int wcol2 = (w & 1);               // 0/1: col-half of wave
    const int quad = lane >> 4;
    const int l15  = lane & 15;
    const int rtb0 = rb * 8;                 // block's first row tile
    const int rta  = rtb0 + wrow2 * 4;       // wave's first row tile
    const int dr   = l15 - quad * 4;         // diag element when dr == r
    const int cbase = jq * 64;               // column-tile base of this split

    const char* xbTb  = (const char*)xbT;
    const char* xbM2b = (const char*)xbM2;
    char* buf0 = (char*)&Bbuf[0][0];
    char* buf1 = (char*)&Bbuf[1][0];

    // ---- prologue: stage A (32 KB) into buf0, async ----
    #pragma unroll
    for (int rnd = 0; rnd < 8; rnd++)
        glds16(xbTb + (size_t)rtb0 * 4096 + rnd * 4096 + t * 16,
               buf0 + rnd * 4096 + t * 16);
    __syncthreads();                          // A staged
    // prefetch B tile jt=0 into buf1 (flies while we read A frags)
    #pragma unroll
    for (int rnd = 0; rnd < 8; rnd++)
        glds16(xbM2b + (size_t)cbase * 4096 + rnd * 4096 + t * 16,
               buf1 + rnd * 4096 + t * 16);

    // A fragments -> registers (ds_read: cannot be rematerialized/sunk)
    bf16x8 A[4][4];
    #pragma unroll
    for (int ti = 0; ti < 4; ti++)
        #pragma unroll
        for (int ks = 0; ks < 4; ks++)
            A[ti][ks] = *(const bf16x8*)(buf0 + (((wrow2 * 4 + ti) * 4 + ks) * 64 + lane) * 16);

    // row labels (sq_i reloaded after the loop)
    int lbli[4][4];
    #pragma unroll
    for (int ti = 0; ti < 4; ti++) {
        int rbase = (rta + ti) * 16 + quad * 4;
        uint4 m01 = *(const uint4*)(meta + rbase);
        uint4 m23 = *(const uint4*)(meta + rbase + 2);
        lbli[ti][0] = (int)m01.y; lbli[ti][1] = (int)m01.w;
        lbli[ti][2] = (int)m23.y; lbli[ti][3] = (int)m23.w;
    }

    float posm[4][4], negm[4][4];
    #pragma unroll
    for (int ti = 0; ti < 4; ti++)
        #pragma unroll
        for (int r = 0; r < 4; r++) { posm[ti][r] = -BIGF; negm[ti][r] = BIGF; }

    #pragma unroll 1
    for (int jt = 0; jt < 8; jt++) {
        __syncthreads();                      // cur buffer staged; next buffer free
        // async prefetch of next B tile into the just-freed buffer
        if (jt < 7) {
            const char* src = xbM2b + (size_t)(cbase + (jt + 1) * 8) * 4096;
            char* dst = (jt & 1) ? buf1 : buf0;
            #pragma unroll
            for (int rnd = 0; rnd < 8; rnd++)
                glds16(src + rnd * 4096 + t * 16, dst + rnd * 4096 + t * 16);
        }
        const char* curb = (jt & 1) ? buf0 : buf1;
        const int cb8 = cbase + jt * 8;

        // column meta for this jt (issued early, consumed per-tj)
        uint2 mv[4];
        #pragma unroll
        for (int tj = 0; tj < 4; tj++)
            mv[tj] = meta[(cb8 + wcol2 * 4 + tj) * 16 + l15];

        #pragma unroll
        for (int tj = 0; tj < 4; tj++) {
            const int tlb = wcol2 * 4 + tj;
            bf16x8 B[4];
            #pragma unroll
            for (int ks = 0; ks < 4; ks++)
                B[ks] = *(const bf16x8*)(curb + ((tlb * 4 + ks) * 64 + lane) * 16);

            float sqj = __uint_as_float(mv[tj].x);
            int lblj  = (int)mv[tj].y;
            f32x4 acc[4];
            #pragma unroll
            for (int ti = 0; ti < 4; ti++) acc[ti] = (f32x4){sqj, sqj, sqj, sqj};
            #pragma unroll
            for (int ks = 0; ks < 4; ks++)
                #pragma unroll
                for (int ti = 0; ti < 4; ti++)
                    acc[ti] = __builtin_amdgcn_mfma_f32_16x16x32_bf16(A[ti][ks], B[ks], acc[ti], 0, 0, 0);

            // acc = sq_j - 2*dot
            int td = (cb8 + tlb) - rta;
            if ((unsigned)td >= 4u) {
                #pragma unroll
                for (int ti = 0; ti < 4; ti++)
                    #pragma unroll
                    for (int r = 0; r < 4; r++) {
                        float s = acc[ti][r];
                        bool same = (lbli[ti][r] == lblj);
                        posm[ti][r] = fmaxf(posm[ti][r], same ? s : -BIGF);
                        negm[ti][r] = fminf(negm[ti][r], same ? BIGF : s);
                    }
            } else {
                #pragma unroll
                for (int ti = 0; ti < 4; ti++)
                    #pragma unroll
                    for (int r = 0; r < 4; r++) {
                        float s = acc[ti][r];
                        bool same = (lbli[ti][r] == lblj);
                        bool isd  = (ti == td) && (dr == r);
                        posm[ti][r] = fmaxf(posm[ti][r], (same && !isd) ? s : -BIGF);
                        negm[ti][r] = fminf(negm[ti][r], same ? BIGF : s);
                    }
            }
        }
    }

    // reload sq_i, reduce across 16 column-lanes, one atomic pair per row
    #pragma unroll
    for (int ti = 0; ti < 4; ti++) {
        int rbase = (rta + ti) * 16 + quad * 4;
        uint4 m01 = *(const uint4*)(meta + rbase);
        uint4 m23 = *(const uint4*)(meta + rbase + 2);
        float sqi[4] = {__uint_as_float(m01.x), __uint_as_float(m01.z),
                        __uint_as_float(m23.x), __uint_as_float(m23.z)};
        #pragma unroll
        for (int r = 0; r < 4; r++) {
            float p = posm[ti][r];
            float n = negm[ti][r];
            #pragma unroll
            for (int m = 8; m >= 1; m >>= 1) {
                p = fmaxf(p, __shfl_xor(p, m));
                n = fminf(n, __shfl_xor(n, m));
            }
            if (l15 == 0) {
                int row = (rta + ti) * 16 + quad * 4 + r;
                float d2p = fmaxf(0.0f, sqi[r] + p);   // no positive -> 0
                float d2n = fmaxf(0.0f, sqi[r] + n);   // clamp bf16-noise negatives
                atomicMax(&posb[row], __float_as_uint(d2p));
                atomicMin(&negb[row], __float_as_uint(d2n));
            }
        }
    }

    // fused finalization: last block computes the loss
    __threadfence();
    __shared__ unsigned lastflag;
    __shared__ float wsum[4];
    __syncthreads();
    if (t == 0) {
        unsigned prev = __hip_atomic_fetch_add(counter, 1u, __ATOMIC_ACQ_REL, __HIP_MEMORY_SCOPE_AGENT);
        lastflag = (prev == NBLK - 1) ? 1u : 0u;
    }
    __syncthreads();
    if (lastflag) {
        __threadfence();
        float mg = margin[0];
        float loss = 0.0f;
        for (int row = t; row < NROW; row += 256) {
            unsigned pb = __hip_atomic_load(&posb[row], __ATOMIC_RELAXED, __HIP_MEMORY_SCOPE_AGENT);
            unsigned nb = __hip_atomic_load(&negb[row], __ATOMIC_RELAXED, __HIP_MEMORY_SCOPE_AGENT);
            float p  = sqrtf(__uint_as_float(pb));
            float ng = sqrtf(__uint_as_float(nb));
            loss += fmaxf(p - ng + mg, 0.0f);
        }
        #pragma unroll
        for (int o = 32; o > 0; o >>= 1) loss += __shfl_down(loss, o);
        if (lane == 0) wsum[w] = loss;
        __syncthreads();
        if (t == 0) out[0] = (wsum[0] + wsum[1] + wsum[2] + wsum[3]) * (1.0f / (float)NROW);
    }
}

extern "C" void kernel_launch(void* const* d_in, const int* in_sizes, int n_in,
                              void* d_out, int out_size, void* d_ws, size_t ws_size,
                              hipStream_t stream) {
    const float* x      = (const float*)d_in[0];
    const int*   lbl    = (const int*)d_in[1];
    const float* margin = (const float*)d_in[2];
    float* out = (float*)d_out;

    const size_t MAT = (size_t)NROW * DIM * 2;
    unsigned short* xbT  = (unsigned short*)d_ws;
    unsigned short* xbM2 = (unsigned short*)((char*)d_ws + MAT);
    uint2*    meta = (uint2*)((char*)d_ws + 2 * MAT);
    unsigned* posb = (unsigned*)((char*)meta + NROW * 8);
    unsigned* negb = posb + NROW;
    unsigned* counter = negb + NROW;

    prep_kernel<<<NROW / 32, 256, 0, stream>>>(x, lbl, xbT, xbM2, meta, posb, negb, counter, out);
    tri_mfma<<<NBLK, 256, 0, stream>>>(xbT, xbM2, meta, posb, negb, counter, margin, out);
}

// Round 7
// 136.266 us; speedup vs baseline: 1.3145x; 1.0148x over previous
//
#include <hip/hip_runtime.h>
#include <hip/hip_bf16.h>

#define NROW 8192
#define DIM  128
#define JSPLIT 8
#define NBLK (64 * JSPLIT)   // 512 blocks
#define BIGF 1e30f

typedef __attribute__((ext_vector_type(8))) short bf16x8;
typedef __attribute__((ext_vector_type(4))) float f32x4;

// ws layout:
//   [0, 2 MB)      xbT  : fragment-major bf16 (A operand), tile*4096 B
//   [2, 4 MB)      xbM2 : same layout, values scaled by -2 (B operand)
//   [4 MB, +64 KB) meta : uint2 { float bits sq[j], lbl[j] }
//   +32 KB posb, +32 KB negb, +16 B counter
// fragment chunk: tile*4096 B; within: ks*1024 + lane*16 bytes; lane=quad*16+l15
// holds rows tile*16+l15, cols ks*32+quad*8..+7

__device__ __forceinline__ unsigned short f2bf(float f) {
    unsigned u = __float_as_uint(f);
    return (unsigned short)((u + 0x7fffu + ((u >> 16) & 1u)) >> 16);   // RNE
}

__device__ __forceinline__ void glds16(const void* g, void* l) {
    __builtin_amdgcn_global_load_lds(
        (const __attribute__((address_space(1))) void*)g,
        (__attribute__((address_space(3))) void*)l,
        16, 0, 0);
}

__global__ __launch_bounds__(256) void prep_kernel(const float* __restrict__ x,
                                                   const int* __restrict__ lbl,
                                                   unsigned short* __restrict__ xbT,
                                                   unsigned short* __restrict__ xbM2,
                                                   uint2* __restrict__ meta,
                                                   unsigned* __restrict__ posb,
                                                   unsigned* __restrict__ negb,
                                                   unsigned* __restrict__ counter,
                                                   float* __restrict__ out) {
    __shared__ unsigned short Al[32][136];
    __shared__ unsigned short Ml[32][136];
    __shared__ float sqp[32][8];

    const int b = blockIdx.x, t = threadIdx.x;
    const int gid = b * 256 + t;
    if (gid < NROW) { posb[gid] = 0u; negb[gid] = __float_as_uint(BIGF); }
    if (gid == 0)   { counter[0] = 0u; out[0] = 0.0f; }

    const int R0  = b * 32;
    const int r   = t >> 3;
    const int seg = t & 7;
    const float* src = x + (size_t)(R0 + r) * DIM + seg * 16;

    float s = 0.0f;
    #pragma unroll
    for (int c4 = 0; c4 < 4; c4++) {
        float4 v = *(const float4*)(src + c4 * 4);
        s += v.x * v.x + v.y * v.y + v.z * v.z + v.w * v.w;
        uint2 ua, um;
        ua.x = (unsigned)f2bf(v.x) | ((unsigned)f2bf(v.y) << 16);
        ua.y = (unsigned)f2bf(v.z) | ((unsigned)f2bf(v.w) << 16);
        um.x = (unsigned)f2bf(-2.0f * v.x) | ((unsigned)f2bf(-2.0f * v.y) << 16);
        um.y = (unsigned)f2bf(-2.0f * v.z) | ((unsigned)f2bf(-2.0f * v.w) << 16);
        *(uint2*)&Al[r][seg * 16 + c4 * 4] = ua;
        *(uint2*)&Ml[r][seg * 16 + c4 * 4] = um;
    }
    sqp[r][seg] = s;
    __syncthreads();

    if (t < 32) {
        float ss = 0.0f;
        #pragma unroll
        for (int q = 0; q < 8; q++) ss += sqp[t][q];
        uint2 mv;
        mv.x = __float_as_uint(ss);
        mv.y = (unsigned)lbl[R0 + t];
        meta[R0 + t] = mv;
    }

    const int ks = t >> 6, lane = t & 63;
    const int q = lane >> 4, l = lane & 15;
    #pragma unroll
    for (int tl = 0; tl < 2; tl++) {
        int row = tl * 16 + l, col = ks * 32 + q * 8;
        uint4 va = *(const uint4*)&Al[row][col];
        uint4 vm = *(const uint4*)&Ml[row][col];
        size_t off = (size_t)(R0 / 16 + tl) * 2048 + ks * 512 + lane * 8;
        *(uint4*)(xbT  + off) = va;
        *(uint4*)(xbM2 + off) = vm;
    }
}

__global__ __launch_bounds__(256) __attribute__((amdgpu_waves_per_eu(2, 2)))
void tri_mfma(const unsigned short* __restrict__ xbT,
              const unsigned short* __restrict__ xbM2,
              const uint2* __restrict__ meta,
              unsigned* __restrict__ posb,
              unsigned* __restrict__ negb,
              unsigned* __restrict__ counter,
              const float* __restrict__ margin,
              float* __restrict__ out) {
    __shared__ uint4 lds[4096];              // 64 KB exactly -> 2 blocks/CU
    char* Ab  = (char*)lds;                  // 32 KB: block's 8 row-tiles
    char* Bb0 = (char*)(lds + 2048);         // 16 KB: B buffer 0 (4 col-tiles)
    char* Bb1 = (char*)(lds + 3072);         // 16 KB: B buffer 1

    const int bid  = blockIdx.x;
    const int rb   = bid >> 3;               // 0..63
    const int jq   = bid & 7;                // 0..7
    const int t    = threadIdx.x;
    const int lane = t & 63;
    const int w    = t >> 6;
    const int quad = lane >> 4;
    const int l15  = lane & 15;
    const int rtb0 = rb * 8;                 // block's first row tile
    const int rta  = rtb0 + w * 2;           // wave's first row tile (2 tiles/wave)
    const int ct0  = jq * 64;                // block's first column tile
    const int dr   = l15 - quad * 4;         // diag element when dr == r

    const char* xbTb  = (const char*)xbT;
    const char* xbM2b = (const char*)xbM2;

    // ---- prologue: stage A (32 KB) and B tile-group 0 (16 KB), async ----
    #pragma unroll
    for (int rnd = 0; rnd < 8; rnd++)
        glds16(xbTb + (size_t)rtb0 * 4096 + rnd * 4096 + t * 16,
               Ab + rnd * 4096 + t * 16);
    #pragma unroll
    for (int rnd = 0; rnd < 4; rnd++)
        glds16(xbM2b + (size_t)ct0 * 4096 + rnd * 4096 + t * 16,
               Bb0 + rnd * 4096 + t * 16);
    __syncthreads();                          // drain all staging

    // A fragments -> registers (32 VGPRs; LDS source never overwritten)
    bf16x8 A[2][4];
    #pragma unroll
    for (int ti = 0; ti < 2; ti++)
        #pragma unroll
        for (int ks = 0; ks < 4; ks++)
            A[ti][ks] = *(const bf16x8*)(Ab + (w * 2 + ti) * 4096 + ks * 1024 + lane * 16);

    // row labels (sq_i reloaded after the loop)
    int lbli[2][4];
    #pragma unroll
    for (int ti = 0; ti < 2; ti++) {
        int rbase = (rta + ti) * 16 + quad * 4;
        uint4 m01 = *(const uint4*)(meta + rbase);
        uint4 m23 = *(const uint4*)(meta + rbase + 2);
        lbli[ti][0] = (int)m01.y; lbli[ti][1] = (int)m01.w;
        lbli[ti][2] = (int)m23.y; lbli[ti][3] = (int)m23.w;
    }

    float posm[2][4], negm[2][4];
    #pragma unroll
    for (int ti = 0; ti < 2; ti++)
        #pragma unroll
        for (int r = 0; r < 4; r++) { posm[ti][r] = -BIGF; negm[ti][r] = BIGF; }

    #pragma unroll 1
    for (int jt = 0; jt < 16; jt++) {
        // async prefetch of next 4 col-tiles into the other buffer
        if (jt < 15) {
            const char* src = xbM2b + (size_t)(ct0 + (jt + 1) * 4) * 4096;
            char* dst = ((jt + 1) & 1) ? Bb1 : Bb0;
            #pragma unroll
            for (int rnd = 0; rnd < 4; rnd++)
                glds16(src + rnd * 4096 + t * 16, dst + rnd * 4096 + t * 16);
        }
        const char* cb = (jt & 1) ? Bb1 : Bb0;

        // column meta for the 4 tiles of this step
        uint2 mv[4];
        #pragma unroll
        for (int c = 0; c < 4; c++)
            mv[c] = meta[(ct0 + jt * 4 + c) * 16 + l15];

        // accumulators seeded with sq_j (C-layout: all 4 regs share col l15)
        f32x4 acc[2][4];
        #pragma unroll
        for (int c = 0; c < 4; c++) {
            float sqj = __uint_as_float(mv[c].x);
            acc[0][c] = (f32x4){sqj, sqj, sqj, sqj};
            acc[1][c] = (f32x4){sqj, sqj, sqj, sqj};
        }

        #pragma unroll
        for (int ks = 0; ks < 4; ks++) {
            bf16x8 B[4];
            #pragma unroll
            for (int c = 0; c < 4; c++)
                B[c] = *(const bf16x8*)(cb + c * 4096 + ks * 1024 + lane * 16);
            #pragma unroll
            for (int ti = 0; ti < 2; ti++)
                #pragma unroll
                for (int c = 0; c < 4; c++)
                    acc[ti][c] = __builtin_amdgcn_mfma_f32_16x16x32_bf16(A[ti][ks], B[c], acc[ti][c], 0, 0, 0);
        }

        // epilogue: acc = sq_j - 2*dot
        #pragma unroll
        for (int c = 0; c < 4; c++) {
            const int ct = ct0 + jt * 4 + c;
            const int lblj = (int)mv[c].y;
            #pragma unroll
            for (int ti = 0; ti < 2; ti++) {
                const bool diag = (ct == rta + ti);
                #pragma unroll
                for (int r = 0; r < 4; r++) {
                    float s = acc[ti][c][r];
                    bool same = (lbli[ti][r] == lblj);
                    bool isd  = diag && (dr == r);
                    posm[ti][r] = fmaxf(posm[ti][r], (same && !isd) ? s : -BIGF);
                    negm[ti][r] = fminf(negm[ti][r], same ? BIGF : s);
                }
            }
        }

        if (jt < 15) __syncthreads();   // drains glds(jt+1); guards buffer reuse
    }

    // reload sq_i, reduce across 16 column-lanes, one atomic pair per row
    #pragma unroll
    for (int ti = 0; ti < 2; ti++) {
        int rbase = (rta + ti) * 16 + quad * 4;
        uint4 m01 = *(const uint4*)(meta + rbase);
        uint4 m23 = *(const uint4*)(meta + rbase + 2);
        float sqi[4] = {__uint_as_float(m01.x), __uint_as_float(m01.z),
                        __uint_as_float(m23.x), __uint_as_float(m23.z)};
        #pragma unroll
        for (int r = 0; r < 4; r++) {
            float p = posm[ti][r];
            float n = negm[ti][r];
            #pragma unroll
            for (int m = 8; m >= 1; m >>= 1) {
                p = fmaxf(p, __shfl_xor(p, m));
                n = fminf(n, __shfl_xor(n, m));
            }
            if (l15 == 0) {
                int row = (rta + ti) * 16 + quad * 4 + r;
                float d2p = fmaxf(0.0f, sqi[r] + p);   // no positive -> 0
                float d2n = fmaxf(0.0f, sqi[r] + n);   // clamp bf16-noise negatives
                atomicMax(&posb[row], __float_as_uint(d2p));
                atomicMin(&negb[row], __float_as_uint(d2n));
            }
        }
    }

    // fused finalization: last block computes the loss
    __threadfence();
    __shared__ unsigned lastflag;
    __shared__ float wsum[4];
    __syncthreads();
    if (t == 0) {
        unsigned prev = __hip_atomic_fetch_add(counter, 1u, __ATOMIC_ACQ_REL, __HIP_MEMORY_SCOPE_AGENT);
        lastflag = (prev == NBLK - 1) ? 1u : 0u;
    }
    __syncthreads();
    if (lastflag) {
        __threadfence();
        float mg = margin[0];
        float loss = 0.0f;
        for (int row = t; row < NROW; row += 256) {
            unsigned pb = __hip_atomic_load(&posb[row], __ATOMIC_RELAXED, __HIP_MEMORY_SCOPE_AGENT);
            unsigned nb = __hip_atomic_load(&negb[row], __ATOMIC_RELAXED, __HIP_MEMORY_SCOPE_AGENT);
            float p  = sqrtf(__uint_as_float(pb));
            float ng = sqrtf(__uint_as_float(nb));
            loss += fmaxf(p - ng + mg, 0.0f);
        }
        #pragma unroll
        for (int o = 32; o > 0; o >>= 1) loss += __shfl_down(loss, o);
        if (lane == 0) wsum[w] = loss;
        __syncthreads();
        if (t == 0) out[0] = (wsum[0] + wsum[1] + wsum[2] + wsum[3]) * (1.0f / (float)NROW);
    }
}

extern "C" void kernel_launch(void* const* d_in, const int* in_sizes, int n_in,
                              void* d_out, int out_size, void* d_ws, size_t ws_size,
                              hipStream_t stream) {
    const float* x      = (const float*)d_in[0];
    const int*   lbl    = (const int*)d_in[1];
    const float* margin = (const float*)d_in[2];
    float* out = (float*)d_out;

    const size_t MAT = (size_t)NROW * DIM * 2;
    unsigned short* xbT  = (unsigned short*)d_ws;
    unsigned short* xbM2 = (unsigned short*)((char*)d_ws + MAT);
    uint2*    meta = (uint2*)((char*)d_ws + 2 * MAT);
    unsigned* posb = (unsigned*)((char*)meta + NROW * 8);
    unsigned* negb = posb + NROW;
    unsigned* counter = negb + NROW;

    prep_kernel<<<NROW / 32, 256, 0, stream>>>(x, lbl, xbT, xbM2, meta, posb, negb, counter, out);
    tri_mfma<<<NBLK, 256, 0, stream>>>(xbT, xbM2, meta, posb, negb, counter, margin, out);
}